// Round 15
// baseline (144.672 us; speedup 1.0000x reference)
//
#include <hip/hip_runtime.h>

// Fused causal MHA forward: B=4, S=2048, D=1024, H=16, Dh=64, fp32 I/O.
// R15: GEMM core BK 64->32, 3-buffer LDS = 72KB -> 2 blocks/CU (the R14
//      profile showed boundary drain with 1 block/CU was the stall, not LDS
//      BW). New 64B-row swizzle c ^= ((r>>1)&3)<<4 (2-way max). Counted
//      vmcnt(3). attn reverted to (256,2) (R14's (256,4) spilled acc_o:
//      VGPR=60 < 64 live). Everything else unchanged.

#define S_LEN 2048
#define DMODEL 1024
#define NB 4

typedef unsigned short u16;
typedef unsigned int u32;
typedef float f32x4 __attribute__((ext_vector_type(4)));
typedef float f32x16 __attribute__((ext_vector_type(16)));
typedef int i32x4 __attribute__((ext_vector_type(4)));
typedef short s16x8 __attribute__((ext_vector_type(8)));
typedef __bf16 bf16x8 __attribute__((ext_vector_type(8)));

__device__ __forceinline__ u16 f2bf(float f) {
  return __builtin_bit_cast(u16, (__bf16)f);
}

__device__ __forceinline__ f32x4 mfma16(s16x8 a, s16x8 b, f32x4 c) {
  return __builtin_amdgcn_mfma_f32_16x16x32_bf16(
      __builtin_bit_cast(bf16x8, a), __builtin_bit_cast(bf16x8, b), c, 0, 0, 0);
}

__device__ __forceinline__ f32x16 mfma32(s16x8 a, s16x8 b, f32x16 c) {
  return __builtin_amdgcn_mfma_f32_32x32x16_bf16(
      __builtin_bit_cast(bf16x8, a), __builtin_bit_cast(bf16x8, b), c, 0, 0, 0);
}

__device__ __forceinline__ int cvtpk(float a, float b) {
  int r;
  asm("v_cvt_pk_bf16_f32 %0, %1, %2" : "=v"(r) : "v"(a), "v"(b));
  return r;
}

__device__ __forceinline__ void gload_lds16(void* lds, const void* g) {
  __builtin_amdgcn_global_load_lds(
      (const __attribute__((address_space(1))) void*)g,
      (__attribute__((address_space(3))) void*)lds, 16, 0, 0);
}

// Swizzled LDS tile, 128-byte rows (attn):  byte = r*128 + (c ^ ((r&7)<<4))
__device__ __forceinline__ s16x8 lds_frag(const u16* lds, int row, int colb) {
  int addr = (row << 7) + (colb ^ ((row & 7) << 4));
  return *(const s16x8*)((const char*)lds + addr);
}

// Swizzled LDS tile, 64-byte rows (BK=32 GEMM): byte = r*64 + (c ^ (((r>>1)&3)<<4))
// Rows 0..7 at fixed col cover all 32 banks; rows 8..15 repeat -> free 2-way.
__device__ __forceinline__ s16x8 lds_frag32(const u16* lds, int row, int colb) {
  int addr = (row << 6) + (colb ^ (((row >> 1) & 3) << 4));
  return *(const s16x8*)((const char*)lds + addr);
}

// ---------------- BK=32 256x128 GEMM core, 2 blocks/CU ----------------
// 512 threads = 8 waves (4M x 2N), wave tile 64x64, BK=32, 3-buffer 72KB LDS.
// Per K-tile: 8 frag reads, 16 MFMA/wave, 3 stage issues; boundary vmcnt(3)
// keeps tile t+2's loads in flight. 2 blocks/CU cover the boundary stalls.
struct G8 {
  u16 As[3][256 * 32];
  u16 Bs[3][128 * 32];
};

template <int NT>
__device__ __forceinline__ void gemm8ph(const u16* __restrict__ A,
                                        const u16* __restrict__ Bt,
                                        int m0, int n0, G8& L,
                                        f32x4 (&acc)[4][4], int tid) {
  constexpr int K = NT * 32;
  const int lane = tid & 63;
  const int wr = (tid >> 6) >> 1, wc = (tid >> 6) & 1;

  auto SA = [&](int buf, int kt) {  // stage A: 256x32 bf16 = 16KB, 2 issues
    const u16* g = A + (size_t)m0 * K + kt * 32;
    #pragma unroll
    for (int it = 0; it < 2; ++it) {
      int o = (tid + it * 512) << 4;
      int r = o >> 6, c = o & 63;
      gload_lds16((char*)L.As[buf] + o,
                  (const char*)(g + (size_t)r * K) + (c ^ (((r >> 1) & 3) << 4)));
    }
  };
  auto SB = [&](int buf, int kt) {  // stage B: 128x32 bf16 = 8KB, 1 issue
    const u16* g = Bt + (size_t)n0 * K + kt * 32;
    int o = tid << 4;
    int r = o >> 6, c = o & 63;
    gload_lds16((char*)L.Bs[buf] + o,
                (const char*)(g + (size_t)r * K) + (c ^ (((r >> 1) & 3) << 4)));
  };

  SA(0, 0); SB(0, 0);
  SA(1, 1); SB(1, 1);                              // outstanding: 6
  asm volatile("s_waitcnt vmcnt(3)" ::: "memory"); // tile0 ready, tile1 in flight
  asm volatile("s_barrier" ::: "memory");

  int cb = 0;  // buffer of tile t
  for (int t = 0; t < NT; ++t) {
    const u16* Ac = L.As[cb];
    const u16* Bc = L.Bs[cb];
    int nxt = cb + 2; if (nxt >= 3) nxt -= 3;
    bool pf = (t + 2 < NT);
    s16x8 a[4], b[4];
    #pragma unroll
    for (int f = 0; f < 4; ++f) {
      a[f] = lds_frag32(Ac, wr * 64 + f * 16 + (lane & 15), (lane >> 4) << 4);
      b[f] = lds_frag32(Bc, wc * 64 + f * 16 + (lane & 15), (lane >> 4) << 4);
    }
    if (pf) { SA(nxt, t + 2); SB(nxt, t + 2); }
    __builtin_amdgcn_s_setprio(1);
    #pragma unroll
    for (int mf = 0; mf < 4; ++mf)
      #pragma unroll
      for (int nf = 0; nf < 4; ++nf)
        acc[mf][nf] = mfma16(a[mf], b[nf], acc[mf][nf]);
    __builtin_amdgcn_s_setprio(0);
    // boundary: tile t+1 (staged during t-1) must be resident; WAR on recycled buf
    if (pf) asm volatile("s_waitcnt vmcnt(3)" ::: "memory");
    else    asm volatile("s_waitcnt vmcnt(0)" ::: "memory");
    asm volatile("s_barrier" ::: "memory");
    cb = (cb + 1 == 3) ? 0 : cb + 1;
  }
}

__global__ __launch_bounds__(256) void castx_kernel(const float4* __restrict__ x,
                                                    ushort4* __restrict__ xb) {
  int i = blockIdx.x * 256 + threadIdx.x;
  float4 v = x[i];
  ushort4 o;
  o.x = f2bf(v.x); o.y = f2bf(v.y); o.z = f2bf(v.z); o.w = f2bf(v.w);
  xb[i] = o;
}

// W [K=1024][N=1024] f32  ->  WT [N][K] bf16 (tiled 32x32 via padded LDS)
__global__ __launch_bounds__(256) void wtrans_kernel(
    const float* __restrict__ W0, const float* __restrict__ W1,
    const float* __restrict__ W2, const float* __restrict__ W3,
    u16* __restrict__ T0, u16* __restrict__ T1, u16* __restrict__ T2, u16* __restrict__ T3) {
  int z = blockIdx.z;
  const float* W = (z == 0) ? W0 : (z == 1) ? W1 : (z == 2) ? W2 : W3;
  u16* T = (z == 0) ? T0 : (z == 1) ? T1 : (z == 2) ? T2 : T3;
  __shared__ float t[32][33];
  int n0 = blockIdx.x << 5, k0 = blockIdx.y << 5;
  int tx = threadIdx.x & 31, ty = threadIdx.x >> 5;
  #pragma unroll
  for (int j = 0; j < 4; ++j)
    t[ty + (j << 3)][tx] = W[(size_t)(k0 + ty + (j << 3)) * DMODEL + n0 + tx];
  __syncthreads();
  #pragma unroll
  for (int j = 0; j < 4; ++j)
    T[(size_t)(n0 + ty + (j << 3)) * DMODEL + k0 + tx] = f2bf(t[tx][ty + (j << 3)]);
}

// Fused QKV projection: xb[8192][1024] @ WqkvT[3072][1024]^T, BK=32 core.
// Q pre-scaled by 0.125*log2(e) -> [b,h,s,d]; K -> [b,h,s,d]; V -> Vt[b,h,d,s].
__global__ __launch_bounds__(512, 4) void qkv8_kernel(
    const u16* __restrict__ xb, const u16* __restrict__ WqkvT,
    u16* __restrict__ Qo, u16* __restrict__ Ko, u16* __restrict__ Vto) {
  __shared__ G8 L;
  int bid = blockIdx.x;                 // 768 blocks, 768 % 8 == 0
  int f = (bid & 7) * 96 + (bid >> 3);  // XCD swizzle (bijective)
  int m0 = (f / 24) << 8, n0 = (f % 24) << 7;
  int tid = threadIdx.x, lane = tid & 63;
  int wr = (tid >> 6) >> 1, wc = (tid >> 6) & 1;
  f32x4 acc[4][4] = {};
  gemm8ph<32>(xb, WqkvT, m0, n0, L, acc, tid);
  int z = n0 >> 10;  // block-uniform: 0=Q, 1=K, 2=V (128-tile lies in one matrix)
  if (z == 2) {
    #pragma unroll
    for (int mf = 0; mf < 4; ++mf)
      #pragma unroll
      for (int nf = 0; nf < 4; ++nf) {
        int rm = m0 + wr * 64 + mf * 16 + ((lane >> 4) << 2);  // token s (i=0)
        int cn = n0 + wc * 64 + nf * 16 + (lane & 15);
        int bb = rm >> 11, s = rm & (S_LEN - 1);
        int c1 = cn & 1023, h = c1 >> 6, d = c1 & 63;
        u32 p0 = (u32)cvtpk(acc[mf][nf][0], acc[mf][nf][1]);
        u32 p1 = (u32)cvtpk(acc[mf][nf][2], acc[mf][nf][3]);
        u32* dst = (u32*)(Vto + (((size_t)((bb << 4) + h)) << 17) + ((size_t)d << 11) + s);
        dst[0] = p0; dst[1] = p1;
      }
  } else {
    float scale = (z == 0) ? 0.18033688f : 1.0f;  // 0.125 * log2(e) for Q
    u16* out = (z == 0) ? Qo : Ko;
    #pragma unroll
    for (int mf = 0; mf < 4; ++mf)
      #pragma unroll
      for (int nf = 0; nf < 4; ++nf)
        #pragma unroll
        for (int i = 0; i < 4; ++i) {
          int rm = m0 + wr * 64 + mf * 16 + ((lane >> 4) << 2) + i;
          int cn = n0 + wc * 64 + nf * 16 + (lane & 15);
          int bb = rm >> 11, s = rm & (S_LEN - 1);
          int c1 = cn & 1023, h = c1 >> 6, d = c1 & 63;
          out[((size_t)((bb << 4) + h) << 17) + ((size_t)s << 6) + d] =
              f2bf(acc[mf][nf][i] * scale);
        }
  }
}

// Flash attention, static softmax, 32x32 MFMA, swapped operands, in-register P.
// (R13 structure; (256,2) bounds -- (256,4) spilled acc_o.)
__global__ __launch_bounds__(256, 2) void attn_kernel(const u16* __restrict__ Q,
                                                      const u16* __restrict__ K,
                                                      const u16* __restrict__ Vt,
                                                      u16* __restrict__ ctx) {
  __shared__ u16 Ks[2][64 * 64];   // [kv][d], swizzled
  __shared__ u16 Vts[2][64 * 64];  // [d][kv], swizzled
  int bh = blockIdx.x, pid = blockIdx.y;
  int tid = threadIdx.x, lane = tid & 63, w = tid >> 6;
  int hi = lane >> 5, lq = lane & 31;
  const u16* Qb = Q + ((size_t)bh << 17);
  const u16* Kb = K + ((size_t)bh << 17);
  const u16* Vtb = Vt + ((size_t)bh << 17);
  int bb = bh >> 4, h = bh & 15;

  auto stage = [&](int buf, int k0) {
    #pragma unroll
    for (int it = 0; it < 2; ++it) {
      int o = (tid + (it << 8)) << 4;
      int r = o >> 7, c = o & 127;
      int csrc = c ^ ((r & 7) << 4);
      gload_lds16((char*)Ks[buf] + o, (const char*)(Kb + ((size_t)(k0 + r) << 6)) + csrc);
      gload_lds16((char*)Vts[buf] + o, (const char*)(Vtb + ((size_t)r << 11) + k0) + csrc);
    }
  };

  for (int ph = 0; ph < 2; ++ph) {
    int qblk = ph ? (15 - pid) : pid;
    int q0 = qblk << 7;
    int qw = q0 + (w << 5);
    int q = qw + lq;

    s16x8 qf[4];
    #pragma unroll
    for (int t = 0; t < 4; ++t)
      qf[t] = *(const s16x8*)(Qb + ((size_t)q << 6) + t * 16 + (hi << 3));

    f32x16 acc_o[2] = {};
    float l_acc = 0.0f;

    int ntiles = (q0 >> 6) + 2;
    int cur = 0;
    stage(0, 0);
    __syncthreads();
    for (int t = 0; t < ntiles; ++t) {
      int k0 = t << 6;
      if (t + 1 < ntiles) stage(cur ^ 1, (t + 1) << 6);
      const u16* Kc = Ks[cur];
      const u16* Vc = Vts[cur];

      #pragma unroll
      for (int kvb = 0; kvb < 2; ++kvb) {
        int kb0 = k0 + kvb * 32;
        if (kb0 <= qw + 31) {
          f32x16 sc = {};
          #pragma unroll
          for (int tt = 0; tt < 4; ++tt) {
            s16x8 kf = lds_frag(Kc, kvb * 32 + lq, tt * 32 + (hi << 4));
            sc = mfma32(kf, qf[tt], sc);
          }
          if (kb0 + 31 > qw) {
            #pragma unroll
            for (int r = 0; r < 16; ++r) {
              int kv = kb0 + (r & 3) + ((r >> 2) << 3) + (hi << 2);
              sc[r] = (kv <= q) ? sc[r] : -3.0e38f;
            }
          }
          #pragma unroll
          for (int r = 0; r < 16; ++r) sc[r] = __builtin_amdgcn_exp2f(sc[r]);
          #pragma unroll
          for (int r = 0; r < 16; ++r) l_acc += sc[r];

          #pragma unroll
          for (int tt = 0; tt < 2; ++tt) {
            int x0 = cvtpk(sc[8 * tt + 0], sc[8 * tt + 1]);
            int x1 = cvtpk(sc[8 * tt + 2], sc[8 * tt + 3]);
            int y0 = cvtpk(sc[8 * tt + 4], sc[8 * tt + 5]);
            int y1 = cvtpk(sc[8 * tt + 6], sc[8 * tt + 7]);
            asm volatile("v_permlane32_swap_b32 %0, %1" : "+v"(x0), "+v"(y0));
            asm volatile("v_permlane32_swap_b32 %0, %1" : "+v"(x1), "+v"(y1));
            i32x4 wi = {x0, x1, y0, y1};
            s16x8 W = __builtin_bit_cast(s16x8, wi);
            int tg = kvb * 2 + tt;
            __builtin_amdgcn_s_setprio(1);
            #pragma unroll
            for (int dblk = 0; dblk < 2; ++dblk) {
              s16x8 vf = lds_frag(Vc, dblk * 32 + lq, tg * 32 + (hi << 4));
              acc_o[dblk] = mfma32(vf, W, acc_o[dblk]);
            }
            __builtin_amdgcn_s_setprio(0);
          }
        }
      }
      __syncthreads();
      cur ^= 1;
    }

    l_acc += __shfl_xor(l_acc, 32);
    float linv = 1.0f / l_acc;
    #pragma unroll
    for (int dblk = 0; dblk < 2; ++dblk)
      #pragma unroll
      for (int rp = 0; rp < 8; ++rp) {
        int r = rp * 2;
        int pk = cvtpk(acc_o[dblk][r] * linv, acc_o[dblk][r + 1] * linv);
        int d = dblk * 32 + (r & 3) + ((r >> 2) << 3) + (hi << 2);
        *(u32*)(ctx + (((size_t)(bb << 11) + q) << 10) + (h << 6) + d) = (u32)pk;
      }
  }
}

// out = ctx @ Wo^T + bo, fp32 output; BK=32 core, 256 blocks = 2 blocks/CU capable.
__global__ __launch_bounds__(512, 4) void out8_kernel(const u16* __restrict__ ctx,
                                                      const u16* __restrict__ WoT,
                                                      const float* __restrict__ bo,
                                                      float* __restrict__ out) {
  __shared__ G8 L;
  int bid = blockIdx.x;
  int f = (bid & 7) * 32 + (bid >> 3);
  int m0 = (f >> 3) << 8, n0 = (f & 7) << 7;
  int tid = threadIdx.x, lane = tid & 63;
  int wr = (tid >> 6) >> 1, wc = (tid >> 6) & 1;
  f32x4 acc[4][4] = {};
  gemm8ph<32>(ctx, WoT, m0, n0, L, acc, tid);
  #pragma unroll
  for (int mf = 0; mf < 4; ++mf)
    #pragma unroll
    for (int nf = 0; nf < 4; ++nf)
      #pragma unroll
      for (int i = 0; i < 4; ++i) {
        int rm = m0 + wr * 64 + mf * 16 + ((lane >> 4) << 2) + i;
        int cn = n0 + wc * 64 + nf * 16 + (lane & 15);
        out[(size_t)rm * DMODEL + cn] = acc[mf][nf][i] + bo[cn];
      }
}

extern "C" void kernel_launch(void* const* d_in, const int* in_sizes, int n_in,
                              void* d_out, int out_size, void* d_ws, size_t ws_size,
                              hipStream_t stream) {
  const float* x  = (const float*)d_in[0];
  const float* Wq = (const float*)d_in[1];
  const float* Wk = (const float*)d_in[2];
  const float* Wv = (const float*)d_in[3];
  const float* Wo = (const float*)d_in[4];
  const float* bo = (const float*)d_in[5];
  float* out = (float*)d_out;

  char* ws = (char*)d_ws;
  const size_t SZ_T = (size_t)NB * S_LEN * DMODEL * 2;  // 16 MiB bf16 activation
  const size_t SZ_W = (size_t)DMODEL * DMODEL * 2;      // 2 MiB bf16 weight
  u16* xb  = (u16*)(ws);
  u16* WqT = (u16*)(ws + SZ_T);                         // WqT|WkT|WvT contiguous
  u16* WkT = (u16*)(ws + SZ_T + 1 * SZ_W);
  u16* WvT = (u16*)(ws + SZ_T + 2 * SZ_W);
  u16* WoT = (u16*)(ws + SZ_T + 3 * SZ_W);
  u16* Qb  = (u16*)(ws + 1 * SZ_T + 4 * SZ_W);
  u16* Kb  = (u16*)(ws + 2 * SZ_T + 4 * SZ_W);
  u16* Vtb = (u16*)(ws + 3 * SZ_T + 4 * SZ_W);
  u16* ctx = xb;  // alias: xb is dead after the QKV projection

  castx_kernel<<<dim3((NB * S_LEN * DMODEL / 4) / 256), dim3(256), 0, stream>>>(
      (const float4*)x, (ushort4*)xb);
  wtrans_kernel<<<dim3(32, 32, 4), dim3(256), 0, stream>>>(Wq, Wk, Wv, Wo,
                                                           WqT, WkT, WvT, WoT);
  qkv8_kernel<<<dim3(768), dim3(512), 0, stream>>>(xb, WqT, Qb, Kb, Vtb);
  attn_kernel<<<dim3(64, 8), dim3(256), 0, stream>>>(Qb, Kb, Vtb, ctx);
  out8_kernel<<<dim3(256), dim3(512), 0, stream>>>(ctx, WoT, bo, out);
}

// Round 16
// 144.603 us; speedup vs baseline: 1.0005x; 1.0005x over previous
//
#include <hip/hip_runtime.h>

// Fused causal MHA forward: B=4, S=2048, D=1024, H=16, Dh=64, fp32 I/O.
// R16 = R15 with launch_bounds reverted to (512,2) on qkv8/out8: the (512,4)
//      bound empirically caps VGPR at 60 (< 64 live accs) -> scratch spill.
//      With BK=32's 72KB LDS and ~88 VGPR, 2 blocks/CU fit BY RESOURCES --
//      no aggressive bound needed. attn (256,2) unchanged.

#define S_LEN 2048
#define DMODEL 1024
#define NB 4

typedef unsigned short u16;
typedef unsigned int u32;
typedef float f32x4 __attribute__((ext_vector_type(4)));
typedef float f32x16 __attribute__((ext_vector_type(16)));
typedef int i32x4 __attribute__((ext_vector_type(4)));
typedef short s16x8 __attribute__((ext_vector_type(8)));
typedef __bf16 bf16x8 __attribute__((ext_vector_type(8)));

__device__ __forceinline__ u16 f2bf(float f) {
  return __builtin_bit_cast(u16, (__bf16)f);
}

__device__ __forceinline__ f32x4 mfma16(s16x8 a, s16x8 b, f32x4 c) {
  return __builtin_amdgcn_mfma_f32_16x16x32_bf16(
      __builtin_bit_cast(bf16x8, a), __builtin_bit_cast(bf16x8, b), c, 0, 0, 0);
}

__device__ __forceinline__ f32x16 mfma32(s16x8 a, s16x8 b, f32x16 c) {
  return __builtin_amdgcn_mfma_f32_32x32x16_bf16(
      __builtin_bit_cast(bf16x8, a), __builtin_bit_cast(bf16x8, b), c, 0, 0, 0);
}

__device__ __forceinline__ int cvtpk(float a, float b) {
  int r;
  asm("v_cvt_pk_bf16_f32 %0, %1, %2" : "=v"(r) : "v"(a), "v"(b));
  return r;
}

__device__ __forceinline__ void gload_lds16(void* lds, const void* g) {
  __builtin_amdgcn_global_load_lds(
      (const __attribute__((address_space(1))) void*)g,
      (__attribute__((address_space(3))) void*)lds, 16, 0, 0);
}

// Swizzled LDS tile, 128-byte rows (attn):  byte = r*128 + (c ^ ((r&7)<<4))
__device__ __forceinline__ s16x8 lds_frag(const u16* lds, int row, int colb) {
  int addr = (row << 7) + (colb ^ ((row & 7) << 4));
  return *(const s16x8*)((const char*)lds + addr);
}

// Swizzled LDS tile, 64-byte rows (BK=32 GEMM): byte = r*64 + (c ^ (((r>>1)&3)<<4))
__device__ __forceinline__ s16x8 lds_frag32(const u16* lds, int row, int colb) {
  int addr = (row << 6) + (colb ^ (((row >> 1) & 3) << 4));
  return *(const s16x8*)((const char*)lds + addr);
}

// ---------------- BK=32 256x128 GEMM core, 2 blocks/CU by resources ----------
// 512 threads = 8 waves (4M x 2N), wave tile 64x64, BK=32, 3-buffer 72KB LDS.
// Per K-tile: 8 frag reads, 16 MFMA/wave, 3 stage issues; boundary vmcnt(3).
struct G8 {
  u16 As[3][256 * 32];
  u16 Bs[3][128 * 32];
};

template <int NT>
__device__ __forceinline__ void gemm8ph(const u16* __restrict__ A,
                                        const u16* __restrict__ Bt,
                                        int m0, int n0, G8& L,
                                        f32x4 (&acc)[4][4], int tid) {
  constexpr int K = NT * 32;
  const int lane = tid & 63;
  const int wr = (tid >> 6) >> 1, wc = (tid >> 6) & 1;

  auto SA = [&](int buf, int kt) {  // stage A: 256x32 bf16 = 16KB, 2 issues
    const u16* g = A + (size_t)m0 * K + kt * 32;
    #pragma unroll
    for (int it = 0; it < 2; ++it) {
      int o = (tid + it * 512) << 4;
      int r = o >> 6, c = o & 63;
      gload_lds16((char*)L.As[buf] + o,
                  (const char*)(g + (size_t)r * K) + (c ^ (((r >> 1) & 3) << 4)));
    }
  };
  auto SB = [&](int buf, int kt) {  // stage B: 128x32 bf16 = 8KB, 1 issue
    const u16* g = Bt + (size_t)n0 * K + kt * 32;
    int o = tid << 4;
    int r = o >> 6, c = o & 63;
    gload_lds16((char*)L.Bs[buf] + o,
                (const char*)(g + (size_t)r * K) + (c ^ (((r >> 1) & 3) << 4)));
  };

  SA(0, 0); SB(0, 0);
  SA(1, 1); SB(1, 1);                              // outstanding: 6
  asm volatile("s_waitcnt vmcnt(3)" ::: "memory"); // tile0 ready, tile1 in flight
  asm volatile("s_barrier" ::: "memory");

  int cb = 0;  // buffer of tile t
  for (int t = 0; t < NT; ++t) {
    const u16* Ac = L.As[cb];
    const u16* Bc = L.Bs[cb];
    int nxt = cb + 2; if (nxt >= 3) nxt -= 3;
    bool pf = (t + 2 < NT);
    s16x8 a[4], b[4];
    #pragma unroll
    for (int f = 0; f < 4; ++f) {
      a[f] = lds_frag32(Ac, wr * 64 + f * 16 + (lane & 15), (lane >> 4) << 4);
      b[f] = lds_frag32(Bc, wc * 64 + f * 16 + (lane & 15), (lane >> 4) << 4);
    }
    if (pf) { SA(nxt, t + 2); SB(nxt, t + 2); }
    __builtin_amdgcn_s_setprio(1);
    #pragma unroll
    for (int mf = 0; mf < 4; ++mf)
      #pragma unroll
      for (int nf = 0; nf < 4; ++nf)
        acc[mf][nf] = mfma16(a[mf], b[nf], acc[mf][nf]);
    __builtin_amdgcn_s_setprio(0);
    // boundary: tile t+1 (staged during t-1) must be resident; WAR on recycled buf
    if (pf) asm volatile("s_waitcnt vmcnt(3)" ::: "memory");
    else    asm volatile("s_waitcnt vmcnt(0)" ::: "memory");
    asm volatile("s_barrier" ::: "memory");
    cb = (cb + 1 == 3) ? 0 : cb + 1;
  }
}

__global__ __launch_bounds__(256) void castx_kernel(const float4* __restrict__ x,
                                                    ushort4* __restrict__ xb) {
  int i = blockIdx.x * 256 + threadIdx.x;
  float4 v = x[i];
  ushort4 o;
  o.x = f2bf(v.x); o.y = f2bf(v.y); o.z = f2bf(v.z); o.w = f2bf(v.w);
  xb[i] = o;
}

// W [K=1024][N=1024] f32  ->  WT [N][K] bf16 (tiled 32x32 via padded LDS)
__global__ __launch_bounds__(256) void wtrans_kernel(
    const float* __restrict__ W0, const float* __restrict__ W1,
    const float* __restrict__ W2, const float* __restrict__ W3,
    u16* __restrict__ T0, u16* __restrict__ T1, u16* __restrict__ T2, u16* __restrict__ T3) {
  int z = blockIdx.z;
  const float* W = (z == 0) ? W0 : (z == 1) ? W1 : (z == 2) ? W2 : W3;
  u16* T = (z == 0) ? T0 : (z == 1) ? T1 : (z == 2) ? T2 : T3;
  __shared__ float t[32][33];
  int n0 = blockIdx.x << 5, k0 = blockIdx.y << 5;
  int tx = threadIdx.x & 31, ty = threadIdx.x >> 5;
  #pragma unroll
  for (int j = 0; j < 4; ++j)
    t[ty + (j << 3)][tx] = W[(size_t)(k0 + ty + (j << 3)) * DMODEL + n0 + tx];
  __syncthreads();
  #pragma unroll
  for (int j = 0; j < 4; ++j)
    T[(size_t)(n0 + ty + (j << 3)) * DMODEL + k0 + tx] = f2bf(t[tx][ty + (j << 3)]);
}

// Fused QKV projection: xb[8192][1024] @ WqkvT[3072][1024]^T, BK=32 core.
// Q pre-scaled by 0.125*log2(e) -> [b,h,s,d]; K -> [b,h,s,d]; V -> Vt[b,h,d,s].
__global__ __launch_bounds__(512, 2) void qkv8_kernel(
    const u16* __restrict__ xb, const u16* __restrict__ WqkvT,
    u16* __restrict__ Qo, u16* __restrict__ Ko, u16* __restrict__ Vto) {
  __shared__ G8 L;
  int bid = blockIdx.x;                 // 768 blocks, 768 % 8 == 0
  int f = (bid & 7) * 96 + (bid >> 3);  // XCD swizzle (bijective)
  int m0 = (f / 24) << 8, n0 = (f % 24) << 7;
  int tid = threadIdx.x, lane = tid & 63;
  int wr = (tid >> 6) >> 1, wc = (tid >> 6) & 1;
  f32x4 acc[4][4] = {};
  gemm8ph<32>(xb, WqkvT, m0, n0, L, acc, tid);
  int z = n0 >> 10;  // block-uniform: 0=Q, 1=K, 2=V (128-tile lies in one matrix)
  if (z == 2) {
    #pragma unroll
    for (int mf = 0; mf < 4; ++mf)
      #pragma unroll
      for (int nf = 0; nf < 4; ++nf) {
        int rm = m0 + wr * 64 + mf * 16 + ((lane >> 4) << 2);  // token s (i=0)
        int cn = n0 + wc * 64 + nf * 16 + (lane & 15);
        int bb = rm >> 11, s = rm & (S_LEN - 1);
        int c1 = cn & 1023, h = c1 >> 6, d = c1 & 63;
        u32 p0 = (u32)cvtpk(acc[mf][nf][0], acc[mf][nf][1]);
        u32 p1 = (u32)cvtpk(acc[mf][nf][2], acc[mf][nf][3]);
        u32* dst = (u32*)(Vto + (((size_t)((bb << 4) + h)) << 17) + ((size_t)d << 11) + s);
        dst[0] = p0; dst[1] = p1;
      }
  } else {
    float scale = (z == 0) ? 0.18033688f : 1.0f;  // 0.125 * log2(e) for Q
    u16* out = (z == 0) ? Qo : Ko;
    #pragma unroll
    for (int mf = 0; mf < 4; ++mf)
      #pragma unroll
      for (int nf = 0; nf < 4; ++nf)
        #pragma unroll
        for (int i = 0; i < 4; ++i) {
          int rm = m0 + wr * 64 + mf * 16 + ((lane >> 4) << 2) + i;
          int cn = n0 + wc * 64 + nf * 16 + (lane & 15);
          int bb = rm >> 11, s = rm & (S_LEN - 1);
          int c1 = cn & 1023, h = c1 >> 6, d = c1 & 63;
          out[((size_t)((bb << 4) + h) << 17) + ((size_t)s << 6) + d] =
              f2bf(acc[mf][nf][i] * scale);
        }
  }
}

// Flash attention, static softmax, 32x32 MFMA, swapped operands, in-register P.
__global__ __launch_bounds__(256, 2) void attn_kernel(const u16* __restrict__ Q,
                                                      const u16* __restrict__ K,
                                                      const u16* __restrict__ Vt,
                                                      u16* __restrict__ ctx) {
  __shared__ u16 Ks[2][64 * 64];   // [kv][d], swizzled
  __shared__ u16 Vts[2][64 * 64];  // [d][kv], swizzled
  int bh = blockIdx.x, pid = blockIdx.y;
  int tid = threadIdx.x, lane = tid & 63, w = tid >> 6;
  int hi = lane >> 5, lq = lane & 31;
  const u16* Qb = Q + ((size_t)bh << 17);
  const u16* Kb = K + ((size_t)bh << 17);
  const u16* Vtb = Vt + ((size_t)bh << 17);
  int bb = bh >> 4, h = bh & 15;

  auto stage = [&](int buf, int k0) {
    #pragma unroll
    for (int it = 0; it < 2; ++it) {
      int o = (tid + (it << 8)) << 4;
      int r = o >> 7, c = o & 127;
      int csrc = c ^ ((r & 7) << 4);
      gload_lds16((char*)Ks[buf] + o, (const char*)(Kb + ((size_t)(k0 + r) << 6)) + csrc);
      gload_lds16((char*)Vts[buf] + o, (const char*)(Vtb + ((size_t)r << 11) + k0) + csrc);
    }
  };

  for (int ph = 0; ph < 2; ++ph) {
    int qblk = ph ? (15 - pid) : pid;
    int q0 = qblk << 7;
    int qw = q0 + (w << 5);
    int q = qw + lq;

    s16x8 qf[4];
    #pragma unroll
    for (int t = 0; t < 4; ++t)
      qf[t] = *(const s16x8*)(Qb + ((size_t)q << 6) + t * 16 + (hi << 3));

    f32x16 acc_o[2] = {};
    float l_acc = 0.0f;

    int ntiles = (q0 >> 6) + 2;
    int cur = 0;
    stage(0, 0);
    __syncthreads();
    for (int t = 0; t < ntiles; ++t) {
      int k0 = t << 6;
      if (t + 1 < ntiles) stage(cur ^ 1, (t + 1) << 6);
      const u16* Kc = Ks[cur];
      const u16* Vc = Vts[cur];

      #pragma unroll
      for (int kvb = 0; kvb < 2; ++kvb) {
        int kb0 = k0 + kvb * 32;
        if (kb0 <= qw + 31) {
          f32x16 sc = {};
          #pragma unroll
          for (int tt = 0; tt < 4; ++tt) {
            s16x8 kf = lds_frag(Kc, kvb * 32 + lq, tt * 32 + (hi << 4));
            sc = mfma32(kf, qf[tt], sc);
          }
          if (kb0 + 31 > qw) {
            #pragma unroll
            for (int r = 0; r < 16; ++r) {
              int kv = kb0 + (r & 3) + ((r >> 2) << 3) + (hi << 2);
              sc[r] = (kv <= q) ? sc[r] : -3.0e38f;
            }
          }
          #pragma unroll
          for (int r = 0; r < 16; ++r) sc[r] = __builtin_amdgcn_exp2f(sc[r]);
          #pragma unroll
          for (int r = 0; r < 16; ++r) l_acc += sc[r];

          #pragma unroll
          for (int tt = 0; tt < 2; ++tt) {
            int x0 = cvtpk(sc[8 * tt + 0], sc[8 * tt + 1]);
            int x1 = cvtpk(sc[8 * tt + 2], sc[8 * tt + 3]);
            int y0 = cvtpk(sc[8 * tt + 4], sc[8 * tt + 5]);
            int y1 = cvtpk(sc[8 * tt + 6], sc[8 * tt + 7]);
            asm volatile("v_permlane32_swap_b32 %0, %1" : "+v"(x0), "+v"(y0));
            asm volatile("v_permlane32_swap_b32 %0, %1" : "+v"(x1), "+v"(y1));
            i32x4 wi = {x0, x1, y0, y1};
            s16x8 W = __builtin_bit_cast(s16x8, wi);
            int tg = kvb * 2 + tt;
            __builtin_amdgcn_s_setprio(1);
            #pragma unroll
            for (int dblk = 0; dblk < 2; ++dblk) {
              s16x8 vf = lds_frag(Vc, dblk * 32 + lq, tg * 32 + (hi << 4));
              acc_o[dblk] = mfma32(vf, W, acc_o[dblk]);
            }
            __builtin_amdgcn_s_setprio(0);
          }
        }
      }
      __syncthreads();
      cur ^= 1;
    }

    l_acc += __shfl_xor(l_acc, 32);
    float linv = 1.0f / l_acc;
    #pragma unroll
    for (int dblk = 0; dblk < 2; ++dblk)
      #pragma unroll
      for (int rp = 0; rp < 8; ++rp) {
        int r = rp * 2;
        int pk = cvtpk(acc_o[dblk][r] * linv, acc_o[dblk][r + 1] * linv);
        int d = dblk * 32 + (r & 3) + ((r >> 2) << 3) + (hi << 2);
        *(u32*)(ctx + (((size_t)(bb << 11) + q) << 10) + (h << 6) + d) = (u32)pk;
      }
  }
}

// out = ctx @ Wo^T + bo, fp32 output; BK=32 core.
__global__ __launch_bounds__(512, 2) void out8_kernel(const u16* __restrict__ ctx,
                                                      const u16* __restrict__ WoT,
                                                      const float* __restrict__ bo,
                                                      float* __restrict__ out) {
  __shared__ G8 L;
  int bid = blockIdx.x;
  int f = (bid & 7) * 32 + (bid >> 3);
  int m0 = (f >> 3) << 8, n0 = (f & 7) << 7;
  int tid = threadIdx.x, lane = tid & 63;
  int wr = (tid >> 6) >> 1, wc = (tid >> 6) & 1;
  f32x4 acc[4][4] = {};
  gemm8ph<32>(ctx, WoT, m0, n0, L, acc, tid);
  #pragma unroll
  for (int mf = 0; mf < 4; ++mf)
    #pragma unroll
    for (int nf = 0; nf < 4; ++nf)
      #pragma unroll
      for (int i = 0; i < 4; ++i) {
        int rm = m0 + wr * 64 + mf * 16 + ((lane >> 4) << 2) + i;
        int cn = n0 + wc * 64 + nf * 16 + (lane & 15);
        out[(size_t)rm * DMODEL + cn] = acc[mf][nf][i] + bo[cn];
      }
}

extern "C" void kernel_launch(void* const* d_in, const int* in_sizes, int n_in,
                              void* d_out, int out_size, void* d_ws, size_t ws_size,
                              hipStream_t stream) {
  const float* x  = (const float*)d_in[0];
  const float* Wq = (const float*)d_in[1];
  const float* Wk = (const float*)d_in[2];
  const float* Wv = (const float*)d_in[3];
  const float* Wo = (const float*)d_in[4];
  const float* bo = (const float*)d_in[5];
  float* out = (float*)d_out;

  char* ws = (char*)d_ws;
  const size_t SZ_T = (size_t)NB * S_LEN * DMODEL * 2;  // 16 MiB bf16 activation
  const size_t SZ_W = (size_t)DMODEL * DMODEL * 2;      // 2 MiB bf16 weight
  u16* xb  = (u16*)(ws);
  u16* WqT = (u16*)(ws + SZ_T);                         // WqT|WkT|WvT contiguous
  u16* WkT = (u16*)(ws + SZ_T + 1 * SZ_W);
  u16* WvT = (u16*)(ws + SZ_T + 2 * SZ_W);
  u16* WoT = (u16*)(ws + SZ_T + 3 * SZ_W);
  u16* Qb  = (u16*)(ws + 1 * SZ_T + 4 * SZ_W);
  u16* Kb  = (u16*)(ws + 2 * SZ_T + 4 * SZ_W);
  u16* Vtb = (u16*)(ws + 3 * SZ_T + 4 * SZ_W);
  u16* ctx = xb;  // alias: xb is dead after the QKV projection

  castx_kernel<<<dim3((NB * S_LEN * DMODEL / 4) / 256), dim3(256), 0, stream>>>(
      (const float4*)x, (ushort4*)xb);
  wtrans_kernel<<<dim3(32, 32, 4), dim3(256), 0, stream>>>(Wq, Wk, Wv, Wo,
                                                           WqT, WkT, WvT, WoT);
  qkv8_kernel<<<dim3(768), dim3(512), 0, stream>>>(xb, WqT, Qb, Kb, Vtb);
  attn_kernel<<<dim3(64, 8), dim3(256), 0, stream>>>(Qb, Kb, Vtb, ctx);
  out8_kernel<<<dim3(256), dim3(512), 0, stream>>>(ctx, WoT, bo, out);
}

// Round 17
// 133.961 us; speedup vs baseline: 1.0800x; 1.0794x over previous
//
#include <hip/hip_runtime.h>

// Fused causal MHA forward: B=4, S=2048, D=1024, H=16, Dh=64, fp32 I/O.
// R17: GEMM core back to BK=64 (R14: best measured, qkv 60.0; R15/16 showed
//      BK=32 is ~4% worse and launch_bounds was a red herring -- VGPR_Count
//      excludes AGPRs, no spill ever happened). attn: pair-staging -- two
//      64-kv tiles staged per barrier ([2][2] buffers, 64KB LDS, still 2
//      blocks/CU), halving all-wave barrier drains; frag math unchanged.

#define S_LEN 2048
#define DMODEL 1024
#define NB 4

typedef unsigned short u16;
typedef unsigned int u32;
typedef float f32x4 __attribute__((ext_vector_type(4)));
typedef float f32x16 __attribute__((ext_vector_type(16)));
typedef int i32x4 __attribute__((ext_vector_type(4)));
typedef short s16x8 __attribute__((ext_vector_type(8)));
typedef __bf16 bf16x8 __attribute__((ext_vector_type(8)));

__device__ __forceinline__ u16 f2bf(float f) {
  return __builtin_bit_cast(u16, (__bf16)f);
}

__device__ __forceinline__ f32x4 mfma16(s16x8 a, s16x8 b, f32x4 c) {
  return __builtin_amdgcn_mfma_f32_16x16x32_bf16(
      __builtin_bit_cast(bf16x8, a), __builtin_bit_cast(bf16x8, b), c, 0, 0, 0);
}

__device__ __forceinline__ f32x16 mfma32(s16x8 a, s16x8 b, f32x16 c) {
  return __builtin_amdgcn_mfma_f32_32x32x16_bf16(
      __builtin_bit_cast(bf16x8, a), __builtin_bit_cast(bf16x8, b), c, 0, 0, 0);
}

__device__ __forceinline__ int cvtpk(float a, float b) {
  int r;
  asm("v_cvt_pk_bf16_f32 %0, %1, %2" : "=v"(r) : "v"(a), "v"(b));
  return r;
}

__device__ __forceinline__ void gload_lds16(void* lds, const void* g) {
  __builtin_amdgcn_global_load_lds(
      (const __attribute__((address_space(1))) void*)g,
      (__attribute__((address_space(3))) void*)lds, 16, 0, 0);
}

// Swizzled LDS tile, 128-byte rows: byte = r*128 + (c ^ ((r&7)<<4))
__device__ __forceinline__ s16x8 lds_frag(const u16* lds, int row, int colb) {
  int addr = (row << 7) + (colb ^ ((row & 7) << 4));
  return *(const s16x8*)((const char*)lds + addr);
}

// ---------------- BK=64 256x128 GEMM core (R14, best measured) ----------------
// 512 threads = 8 waves (4M x 2N), wave tile 64x64, BK=64, 3-buffer 144KB LDS.
// Counted vmcnt(6); no mid-phase fences (compiler interleaves lgkm with MFMA).
struct G8 {
  u16 As[3][256 * 64];
  u16 Bs[3][128 * 64];
};

template <int NT>
__device__ __forceinline__ void gemm8ph(const u16* __restrict__ A,
                                        const u16* __restrict__ Bt,
                                        int m0, int n0, G8& L,
                                        f32x4 (&acc)[4][4], int tid) {
  constexpr int K = NT * 64;
  const int lane = tid & 63;
  const int wr = (tid >> 6) >> 1, wc = (tid >> 6) & 1;

  auto SA = [&](int buf, int kt) {  // stage A half: 256x64 bf16, 4 issues
    const u16* g = A + (size_t)m0 * K + kt * 64;
    #pragma unroll
    for (int it = 0; it < 4; ++it) {
      int o = (tid + it * 512) << 4;
      int r = o >> 7, c = o & 127;
      gload_lds16((char*)L.As[buf] + o,
                  (const char*)(g + (size_t)r * K) + (c ^ ((r & 7) << 4)));
    }
  };
  auto SB = [&](int buf, int kt) {  // stage B half: 128x64 bf16, 2 issues
    const u16* g = Bt + (size_t)n0 * K + kt * 64;
    #pragma unroll
    for (int it = 0; it < 2; ++it) {
      int o = (tid + it * 512) << 4;
      int r = o >> 7, c = o & 127;
      gload_lds16((char*)L.Bs[buf] + o,
                  (const char*)(g + (size_t)r * K) + (c ^ ((r & 7) << 4)));
    }
  };

  SA(0, 0); SB(0, 0);
  SA(1, 1); SB(1, 1);                              // outstanding: 12
  asm volatile("s_waitcnt vmcnt(6)" ::: "memory"); // tile0 ready, tile1 in flight
  asm volatile("s_barrier" ::: "memory");

  int cb = 0;  // buffer of tile t
  for (int t = 0; t < NT; ++t) {
    const u16* Ac = L.As[cb];
    const u16* Bc = L.Bs[cb];
    int nxt = cb + 2; if (nxt >= 3) nxt -= 3;
    bool pf = (t + 2 < NT);
    #pragma unroll
    for (int ph = 0; ph < 2; ++ph) {
      s16x8 a[4], b[4];
      #pragma unroll
      for (int f = 0; f < 4; ++f) {
        a[f] = lds_frag(Ac, wr * 64 + f * 16 + (lane & 15), ph * 64 + ((lane >> 4) << 4));
        b[f] = lds_frag(Bc, wc * 64 + f * 16 + (lane & 15), ph * 64 + ((lane >> 4) << 4));
      }
      if (pf) { if (ph == 0) SA(nxt, t + 2); else SB(nxt, t + 2); }
      __builtin_amdgcn_s_setprio(1);
      #pragma unroll
      for (int mf = 0; mf < 4; ++mf)
        #pragma unroll
        for (int nf = 0; nf < 4; ++nf)
          acc[mf][nf] = mfma16(a[mf], b[nf], acc[mf][nf]);
      __builtin_amdgcn_s_setprio(0);
    }
    // K-tile boundary: tile t+1 (staged during t-1) must be in LDS; WAR on buf.
    if (pf) asm volatile("s_waitcnt vmcnt(6)" ::: "memory");
    else    asm volatile("s_waitcnt vmcnt(0)" ::: "memory");
    asm volatile("s_barrier" ::: "memory");
    cb = (cb + 1 == 3) ? 0 : cb + 1;
  }
}

__global__ __launch_bounds__(256) void castx_kernel(const float4* __restrict__ x,
                                                    ushort4* __restrict__ xb) {
  int i = blockIdx.x * 256 + threadIdx.x;
  float4 v = x[i];
  ushort4 o;
  o.x = f2bf(v.x); o.y = f2bf(v.y); o.z = f2bf(v.z); o.w = f2bf(v.w);
  xb[i] = o;
}

// W [K=1024][N=1024] f32  ->  WT [N][K] bf16 (tiled 32x32 via padded LDS)
__global__ __launch_bounds__(256) void wtrans_kernel(
    const float* __restrict__ W0, const float* __restrict__ W1,
    const float* __restrict__ W2, const float* __restrict__ W3,
    u16* __restrict__ T0, u16* __restrict__ T1, u16* __restrict__ T2, u16* __restrict__ T3) {
  int z = blockIdx.z;
  const float* W = (z == 0) ? W0 : (z == 1) ? W1 : (z == 2) ? W2 : W3;
  u16* T = (z == 0) ? T0 : (z == 1) ? T1 : (z == 2) ? T2 : T3;
  __shared__ float t[32][33];
  int n0 = blockIdx.x << 5, k0 = blockIdx.y << 5;
  int tx = threadIdx.x & 31, ty = threadIdx.x >> 5;
  #pragma unroll
  for (int j = 0; j < 4; ++j)
    t[ty + (j << 3)][tx] = W[(size_t)(k0 + ty + (j << 3)) * DMODEL + n0 + tx];
  __syncthreads();
  #pragma unroll
  for (int j = 0; j < 4; ++j)
    T[(size_t)(n0 + ty + (j << 3)) * DMODEL + k0 + tx] = f2bf(t[tx][ty + (j << 3)]);
}

// Fused QKV projection: xb[8192][1024] @ WqkvT[3072][1024]^T, BK=64 core.
// Q pre-scaled by 0.125*log2(e) -> [b,h,s,d]; K -> [b,h,s,d]; V -> Vt[b,h,d,s].
__global__ __launch_bounds__(512, 2) void qkv8_kernel(
    const u16* __restrict__ xb, const u16* __restrict__ WqkvT,
    u16* __restrict__ Qo, u16* __restrict__ Ko, u16* __restrict__ Vto) {
  __shared__ G8 L;
  int bid = blockIdx.x;                 // 768 blocks, 768 % 8 == 0
  int f = (bid & 7) * 96 + (bid >> 3);  // XCD swizzle (bijective)
  int m0 = (f / 24) << 8, n0 = (f % 24) << 7;
  int tid = threadIdx.x, lane = tid & 63;
  int wr = (tid >> 6) >> 1, wc = (tid >> 6) & 1;
  f32x4 acc[4][4] = {};
  gemm8ph<16>(xb, WqkvT, m0, n0, L, acc, tid);
  int z = n0 >> 10;  // block-uniform: 0=Q, 1=K, 2=V (128-tile lies in one matrix)
  if (z == 2) {
    #pragma unroll
    for (int mf = 0; mf < 4; ++mf)
      #pragma unroll
      for (int nf = 0; nf < 4; ++nf) {
        int rm = m0 + wr * 64 + mf * 16 + ((lane >> 4) << 2);  // token s (i=0)
        int cn = n0 + wc * 64 + nf * 16 + (lane & 15);
        int bb = rm >> 11, s = rm & (S_LEN - 1);
        int c1 = cn & 1023, h = c1 >> 6, d = c1 & 63;
        u32 p0 = (u32)cvtpk(acc[mf][nf][0], acc[mf][nf][1]);
        u32 p1 = (u32)cvtpk(acc[mf][nf][2], acc[mf][nf][3]);
        u32* dst = (u32*)(Vto + (((size_t)((bb << 4) + h)) << 17) + ((size_t)d << 11) + s);
        dst[0] = p0; dst[1] = p1;
      }
  } else {
    float scale = (z == 0) ? 0.18033688f : 1.0f;  // 0.125 * log2(e) for Q
    u16* out = (z == 0) ? Qo : Ko;
    #pragma unroll
    for (int mf = 0; mf < 4; ++mf)
      #pragma unroll
      for (int nf = 0; nf < 4; ++nf)
        #pragma unroll
        for (int i = 0; i < 4; ++i) {
          int rm = m0 + wr * 64 + mf * 16 + ((lane >> 4) << 2) + i;
          int cn = n0 + wc * 64 + nf * 16 + (lane & 15);
          int bb = rm >> 11, s = rm & (S_LEN - 1);
          int c1 = cn & 1023, h = c1 >> 6, d = c1 & 63;
          out[((size_t)((bb << 4) + h) << 17) + ((size_t)s << 6) + d] =
              f2bf(acc[mf][nf][i] * scale);
        }
  }
}

// Flash attention, static softmax, 32x32 MFMA, swapped operands, in-register P.
// R17: pair-staging -- two 64-kv tiles per barrier ([2][2] buffers, 64KB LDS),
// halving all-wave barrier drains. Frag layout per tile unchanged.
__global__ __launch_bounds__(256, 2) void attn_kernel(const u16* __restrict__ Q,
                                                      const u16* __restrict__ K,
                                                      const u16* __restrict__ Vt,
                                                      u16* __restrict__ ctx) {
  __shared__ u16 Ks[2][2][64 * 64];   // [pairbuf][sub][kv][d], swizzled
  __shared__ u16 Vts[2][2][64 * 64];  // [pairbuf][sub][d][kv], swizzled
  int bh = blockIdx.x, pid = blockIdx.y;
  int tid = threadIdx.x, lane = tid & 63, w = tid >> 6;
  int hi = lane >> 5, lq = lane & 31;
  const u16* Qb = Q + ((size_t)bh << 17);
  const u16* Kb = K + ((size_t)bh << 17);
  const u16* Vtb = Vt + ((size_t)bh << 17);
  int bb = bh >> 4, h = bh & 15;

  auto stage_pair = [&](int pb, int tp) {
    #pragma unroll
    for (int s = 0; s < 2; ++s) {
      int k0 = (tp * 2 + s) << 6;
      #pragma unroll
      for (int it = 0; it < 2; ++it) {
        int o = (tid + (it << 8)) << 4;
        int r = o >> 7, c = o & 127;
        int csrc = c ^ ((r & 7) << 4);
        gload_lds16((char*)Ks[pb][s] + o,
                    (const char*)(Kb + ((size_t)(k0 + r) << 6)) + csrc);
        gload_lds16((char*)Vts[pb][s] + o,
                    (const char*)(Vtb + ((size_t)r << 11) + k0) + csrc);
      }
    }
  };

  for (int ph = 0; ph < 2; ++ph) {
    int qblk = ph ? (15 - pid) : pid;
    int q0 = qblk << 7;
    int qw = q0 + (w << 5);
    int q = qw + lq;

    s16x8 qf[4];
    #pragma unroll
    for (int t = 0; t < 4; ++t)
      qf[t] = *(const s16x8*)(Qb + ((size_t)q << 6) + t * 16 + (hi << 3));

    f32x16 acc_o[2] = {};
    float l_acc = 0.0f;

    int npairs = (q0 >> 7) + 1;  // ntiles = (q0>>6)+2 is even; pairs of 2 tiles
    stage_pair(0, 0);
    __syncthreads();
    for (int tp = 0; tp < npairs; ++tp) {
      int pb = tp & 1;
      if (tp + 1 < npairs) stage_pair(pb ^ 1, tp + 1);
      #pragma unroll
      for (int s = 0; s < 2; ++s) {
        int t = tp * 2 + s;
        int k0 = t << 6;
        if (k0 > qw + 31) continue;  // wave-uniform tail skip
        const u16* Kc = Ks[pb][s];
        const u16* Vc = Vts[pb][s];

        #pragma unroll
        for (int kvb = 0; kvb < 2; ++kvb) {
          int kb0 = k0 + kvb * 32;
          if (kb0 <= qw + 31) {
            f32x16 sc = {};
            #pragma unroll
            for (int tt = 0; tt < 4; ++tt) {
              s16x8 kf = lds_frag(Kc, kvb * 32 + lq, tt * 32 + (hi << 4));
              sc = mfma32(kf, qf[tt], sc);
            }
            if (kb0 + 31 > qw) {
              #pragma unroll
              for (int r = 0; r < 16; ++r) {
                int kv = kb0 + (r & 3) + ((r >> 2) << 3) + (hi << 2);
                sc[r] = (kv <= q) ? sc[r] : -3.0e38f;
              }
            }
            #pragma unroll
            for (int r = 0; r < 16; ++r) sc[r] = __builtin_amdgcn_exp2f(sc[r]);
            #pragma unroll
            for (int r = 0; r < 16; ++r) l_acc += sc[r];

            #pragma unroll
            for (int tt = 0; tt < 2; ++tt) {
              int x0 = cvtpk(sc[8 * tt + 0], sc[8 * tt + 1]);
              int x1 = cvtpk(sc[8 * tt + 2], sc[8 * tt + 3]);
              int y0 = cvtpk(sc[8 * tt + 4], sc[8 * tt + 5]);
              int y1 = cvtpk(sc[8 * tt + 6], sc[8 * tt + 7]);
              asm volatile("v_permlane32_swap_b32 %0, %1" : "+v"(x0), "+v"(y0));
              asm volatile("v_permlane32_swap_b32 %0, %1" : "+v"(x1), "+v"(y1));
              i32x4 wi = {x0, x1, y0, y1};
              s16x8 W = __builtin_bit_cast(s16x8, wi);
              int tg = kvb * 2 + tt;
              __builtin_amdgcn_s_setprio(1);
              #pragma unroll
              for (int dblk = 0; dblk < 2; ++dblk) {
                s16x8 vf = lds_frag(Vc, dblk * 32 + lq, tg * 32 + (hi << 4));
                acc_o[dblk] = mfma32(vf, W, acc_o[dblk]);
              }
              __builtin_amdgcn_s_setprio(0);
            }
          }
        }
      }
      __syncthreads();  // one all-wave drain per PAIR of tiles
    }

    l_acc += __shfl_xor(l_acc, 32);
    float linv = 1.0f / l_acc;
    #pragma unroll
    for (int dblk = 0; dblk < 2; ++dblk)
      #pragma unroll
      for (int rp = 0; rp < 8; ++rp) {
        int r = rp * 2;
        int pk = cvtpk(acc_o[dblk][r] * linv, acc_o[dblk][r + 1] * linv);
        int d = dblk * 32 + (r & 3) + ((r >> 2) << 3) + (hi << 2);
        *(u32*)(ctx + (((size_t)(bb << 11) + q) << 10) + (h << 6) + d) = (u32)pk;
      }
  }
}

// out = ctx @ Wo^T + bo, fp32 output; BK=64 core, 256 blocks.
__global__ __launch_bounds__(512, 2) void out8_kernel(const u16* __restrict__ ctx,
                                                      const u16* __restrict__ WoT,
                                                      const float* __restrict__ bo,
                                                      float* __restrict__ out) {
  __shared__ G8 L;
  int bid = blockIdx.x;
  int f = (bid & 7) * 32 + (bid >> 3);
  int m0 = (f >> 3) << 8, n0 = (f & 7) << 7;
  int tid = threadIdx.x, lane = tid & 63;
  int wr = (tid >> 6) >> 1, wc = (tid >> 6) & 1;
  f32x4 acc[4][4] = {};
  gemm8ph<16>(ctx, WoT, m0, n0, L, acc, tid);
  #pragma unroll
  for (int mf = 0; mf < 4; ++mf)
    #pragma unroll
    for (int nf = 0; nf < 4; ++nf)
      #pragma unroll
      for (int i = 0; i < 4; ++i) {
        int rm = m0 + wr * 64 + mf * 16 + ((lane >> 4) << 2) + i;
        int cn = n0 + wc * 64 + nf * 16 + (lane & 15);
        out[(size_t)rm * DMODEL + cn] = acc[mf][nf][i] + bo[cn];
      }
}

extern "C" void kernel_launch(void* const* d_in, const int* in_sizes, int n_in,
                              void* d_out, int out_size, void* d_ws, size_t ws_size,
                              hipStream_t stream) {
  const float* x  = (const float*)d_in[0];
  const float* Wq = (const float*)d_in[1];
  const float* Wk = (const float*)d_in[2];
  const float* Wv = (const float*)d_in[3];
  const float* Wo = (const float*)d_in[4];
  const float* bo = (const float*)d_in[5];
  float* out = (float*)d_out;

  char* ws = (char*)d_ws;
  const size_t SZ_T = (size_t)NB * S_LEN * DMODEL * 2;  // 16 MiB bf16 activation
  const size_t SZ_W = (size_t)DMODEL * DMODEL * 2;      // 2 MiB bf16 weight
  u16* xb  = (u16*)(ws);
  u16* WqT = (u16*)(ws + SZ_T);                         // WqT|WkT|WvT contiguous
  u16* WkT = (u16*)(ws + SZ_T + 1 * SZ_W);
  u16* WvT = (u16*)(ws + SZ_T + 2 * SZ_W);
  u16* WoT = (u16*)(ws + SZ_T + 3 * SZ_W);
  u16* Qb  = (u16*)(ws + 1 * SZ_T + 4 * SZ_W);
  u16* Kb  = (u16*)(ws + 2 * SZ_T + 4 * SZ_W);
  u16* Vtb = (u16*)(ws + 3 * SZ_T + 4 * SZ_W);
  u16* ctx = xb;  // alias: xb is dead after the QKV projection

  castx_kernel<<<dim3((NB * S_LEN * DMODEL / 4) / 256), dim3(256), 0, stream>>>(
      (const float4*)x, (ushort4*)xb);
  wtrans_kernel<<<dim3(32, 32, 4), dim3(256), 0, stream>>>(Wq, Wk, Wv, Wo,
                                                           WqT, WkT, WvT, WoT);
  qkv8_kernel<<<dim3(768), dim3(512), 0, stream>>>(xb, WqT, Qb, Kb, Vtb);
  attn_kernel<<<dim3(64, 8), dim3(256), 0, stream>>>(Qb, Kb, Vtb, ctx);
  out8_kernel<<<dim3(256), dim3(512), 0, stream>>>(ctx, WoT, bo, out);
}